// Round 5
// baseline (1288.405 us; speedup 1.0000x reference)
//
#include <hip/hip_runtime.h>

namespace {
constexpr int N_NODES = 10000;
constexpr int DEG = 16;
constexpr int D = DEG + 1;            // 17 neighbors incl self-loop
constexpr int F_IN = 512;
constexpr int HID = 16;
constexpr int NC = 32;
constexpr int E0 = N_NODES * DEG;     // 160000
constexpr float SIGB  = 0.10009765625f;    // bf16(0.1)
constexpr float NORMB = 0.058837890625f;   // bf16(bf16(17^-0.5)^2), dinv=0.24267578125

// round-to-nearest-even f32 -> bf16 value (kept in f32) — matches ml_dtypes
__device__ __forceinline__ float bfr(float v) {
  unsigned x = __float_as_uint(v);
  x = (x + 0x7fffu + ((x >> 16) & 1u)) & 0xffff0000u;
  return __uint_as_float(x);
}
}  // namespace

// static device scratch (all bf16-valued f32)
__device__ float g_h1[N_NODES * HID];
__device__ float g_r1[N_NODES * HID];
__device__ float g_h2[N_NODES * NC];
__device__ float g_sq1[N_NODES * D];
__device__ float g_sq2[N_NODES * D];
__device__ float g_sf1[N_NODES];
__device__ float g_sf2[N_NODES];

// h1[i][j] = bf16chain( sum_k bf16(x_ik)*bf16(W1_kj) ) + bf16(b1_j), all ops bf16-rounded
__global__ void k_lin1(const float* __restrict__ x, const float* __restrict__ W1,
                       const float* __restrict__ b1) {
  int g = blockIdx.x * blockDim.x + threadIdx.x;
  if (g >= N_NODES * HID) return;
  int i = g >> 4, j = g & 15;
  const float* xr = x + (size_t)i * F_IN;
  float acc = 0.f;
  for (int k = 0; k < F_IN; ++k) {
    float p = bfr(bfr(xr[k]) * bfr(W1[k * HID + j]));
    acc = bfr(acc + p);
  }
  g_h1[g] = bfr(acc + bfr(b1[j]));
}

// h2[i][j] = bf16chain( sum_k r1_ik * bf16(W2_kj) ) + bf16(b2_j)
__global__ void k_lin2(const float* __restrict__ W2, const float* __restrict__ b2) {
  int g = blockIdx.x * blockDim.x + threadIdx.x;
  if (g >= N_NODES * NC) return;
  int i = g >> 5, j = g & 31;
  float acc = 0.f;
#pragma unroll
  for (int k = 0; k < HID; ++k) {
    float p = bfr(g_r1[i * HID + k] * bfr(W2[k * NC + j]));
    acc = bfr(acc + p);
  }
  g_h2[g] = bfr(acc + bfr(b2[j]));
}

// Per node i (one wave of 64): neighbor tile, sq (seq-bf16), self-kernel mean
// (flat a-major seq-bf16 over 289), aggregation (seq-bf16, edges then self-loop).
template <int H, bool LOGSM>
__global__ void k_build(const float* __restrict__ hpre, const int* __restrict__ row0,
                        float* __restrict__ selfm, float* __restrict__ sqb,
                        float* __restrict__ relu_out, float* __restrict__ out0) {
  __shared__ int nidx[D];
  __shared__ float T[D * H];
  __shared__ float sq[D];
  __shared__ float sterm[D * D];
  __shared__ float earr[32];
  __shared__ float lsv;
  int i = blockIdx.x, t = threadIdx.x;  // 0..63 (one wave)
  if (t < D) nidx[t] = (t < DEG) ? row0[i * DEG + t] : i;
  __syncthreads();
  for (int e = t; e < D * H; e += 64) {
    int d = e / H, h = e - d * H;
    T[e] = hpre[(size_t)nidx[d] * H + h];
  }
  __syncthreads();
  if (t < D) {
    float s = 0.f;  // seq bf16 chain over h ascending: sum(hn*hn)
#pragma unroll
    for (int h = 0; h < H; ++h) { float v = T[t * H + h]; s = bfr(s + bfr(v * v)); }
    sq[t] = s;
    sqb[i * D + t] = s;
  }
  __syncthreads();
  // self-kernel terms over D*D pairs (einsum dot = seq-bf16 over h)
  for (int p = t; p < D * D; p += 64) {
    int a = p / D, b = p - a * D;
    const float* ra = T + a * H;
    const float* rb = T + b * H;
    float dot = 0.f;
#pragma unroll
    for (int q = 0; q < H; ++q) dot = bfr(dot + bfr(ra[q] * rb[q]));
    float d2 = bfr(bfr(sq[a] + sq[b]) - bfr(2.f * dot));
    float arg = bfr((-d2) / SIGB);
    sterm[p] = bfr(__expf(arg) == __expf(arg) ? expf(arg) : expf(arg));
  }
  __syncthreads();
  if (t == 0) {  // flat (a-major) seq-bf16 mean over 289
    float s = 0.f;
#pragma unroll 1
    for (int p = 0; p < D * D; ++p) s = bfr(s + sterm[p]);
    selfm[i] = bfr(s / 289.0f);
  }
  // aggregation: acc = seq-bf16 sum of bf16(NORMB*h[row_e]), edge order then self-loop
  if constexpr (!LOGSM) {
    if (t < H) {
      float acc = 0.f;
#pragma unroll
      for (int d = 0; d < DEG; ++d) acc = bfr(acc + bfr(NORMB * T[d * H + t]));
      acc = bfr(acc + bfr(NORMB * T[DEG * H + t]));
      relu_out[i * H + t] = fmaxf(acc, 0.f);
    }
  } else {
    int j = t & 31;
    float v = 0.f;
#pragma unroll
    for (int d = 0; d < DEG; ++d) v = bfr(v + bfr(NORMB * T[d * H + j]));
    v = bfr(v + bfr(NORMB * T[DEG * H + j]));
    // log_softmax: shifted = bf16(v - max); e = bf16(exp); sum seq-bf16 j=0..31; out = bf16(sh - log)
    float m = v;
#pragma unroll
    for (int off = 32; off; off >>= 1) m = fmaxf(m, __shfl_xor(m, off));
    float sh = bfr(v - m);
    if (t < 32) earr[t] = bfr(expf(sh));
    __syncthreads();
    if (t == 0) {
      float s = 0.f;
#pragma unroll 1
      for (int q = 0; q < 32; ++q) s = bfr(s + earr[q]);
      lsv = bfr(logf(s));
    }
    __syncthreads();
    if (t < 32) out0[i * 32 + t] = bfr(sh - lsv);
  }
}

// Per col-node c: 16 edges x (17x17) pairs; terms staged in LDS, then per-edge
// flat a-major seq-bf16 mean; mmd = bf16(bf16(sf_r+sf_c) - 2*cross).
template <int H>
__global__ void k_cross(const float* __restrict__ hpre, const float* __restrict__ sqb,
                        const float* __restrict__ selfm, const int* __restrict__ row0,
                        float* __restrict__ outm) {
  constexpr int DH = D * H;
  __shared__ float hc[DH];
  __shared__ float sqc[D];
  __shared__ float cterm[DEG * D * D];  // [k][a*17+b], 4624 floats
  int c = blockIdx.x, t = threadIdx.x;  // 0..319
  for (int e = t; e < DH; e += 320) {
    int d = e / H, h = e - d * H;
    int idx = (d < DEG) ? row0[c * DEG + d] : c;
    hc[e] = hpre[(size_t)idx * H + h];
  }
  if (t < D) sqc[t] = sqb[c * D + t];
  __syncthreads();
  if (t < DEG * D) {
    int k = t / D, a = t - k * D;
    int r = row0[c * DEG + k];
    int idx = (a < DEG) ? row0[r * DEG + a] : r;
    const float* hr = hpre + (size_t)idx * H;
    float rv[H];
#pragma unroll
    for (int q = 0; q < H; ++q) rv[q] = hr[q];
    float sqra = sqb[r * D + a];
    float* out_t = cterm + k * (D * D) + a * D;
    for (int b = 0; b < D; ++b) {
      const float* rb = hc + b * H;
      float dot = 0.f;
#pragma unroll
      for (int q = 0; q < H; ++q) dot = bfr(dot + bfr(rv[q] * rb[q]));
      float d2 = bfr(bfr(sqra + sqc[b]) - bfr(2.f * dot));
      float arg = bfr((-d2) / SIGB);
      out_t[b] = bfr(expf(arg));
    }
  }
  __syncthreads();
  if (t < DEG) {
    const float* src = cterm + t * (D * D);
    float s = 0.f;
#pragma unroll 1
    for (int p = 0; p < D * D; ++p) s = bfr(s + src[p]);
    float cross = bfr(s / 289.0f);
    int r = row0[c * DEG + t];
    float mmd = bfr(bfr(selfm[r] + selfm[c]) - 2.f * cross);
    outm[c * DEG + t] = mmd;
  }
  if (t == DEG) outm[E0 + c] = 0.0f;  // self-loop: cross chain == self chain -> exactly 0
}

extern "C" void kernel_launch(void* const* d_in, const int* in_sizes, int n_in,
                              void* d_out, int out_size, void* d_ws, size_t ws_size,
                              hipStream_t stream) {
  const float* x  = (const float*)d_in[0];
  const int* edge_index = (const int*)d_in[1];
  const float* W1 = (const float*)d_in[2];
  const float* b1 = (const float*)d_in[3];
  const float* W2 = (const float*)d_in[4];
  const float* b2 = (const float*)d_in[5];
  const int* row0 = edge_index;  // first E0 entries = row (col = e/16 by construction)
  (void)d_ws; (void)ws_size;

  float *h1, *r1, *h2, *sq1, *sq2, *sf1, *sf2;
  hipGetSymbolAddress((void**)&h1,  HIP_SYMBOL(g_h1));
  hipGetSymbolAddress((void**)&r1,  HIP_SYMBOL(g_r1));
  hipGetSymbolAddress((void**)&h2,  HIP_SYMBOL(g_h2));
  hipGetSymbolAddress((void**)&sq1, HIP_SYMBOL(g_sq1));
  hipGetSymbolAddress((void**)&sq2, HIP_SYMBOL(g_sq2));
  hipGetSymbolAddress((void**)&sf1, HIP_SYMBOL(g_sf1));
  hipGetSymbolAddress((void**)&sf2, HIP_SYMBOL(g_sf2));

  float* out0 = (float*)d_out;             // log_softmax [10000,32]
  float* out1 = out0 + N_NODES * NC;       // mmd1 [170000]
  float* out2 = out1 + (E0 + N_NODES);     // mmd2 [170000]

  k_lin1<<<(N_NODES * HID + 255) / 256, 256, 0, stream>>>(x, W1, b1);
  k_build<HID, false><<<N_NODES, 64, 0, stream>>>(h1, row0, sf1, sq1, r1, nullptr);
  k_cross<HID><<<N_NODES, 320, 0, stream>>>(h1, sq1, sf1, row0, out1);
  k_lin2<<<(N_NODES * NC + 255) / 256, 256, 0, stream>>>(W2, b2);
  k_build<NC, true><<<N_NODES, 64, 0, stream>>>(h2, row0, sf2, sq2, nullptr, out0);
  k_cross<NC><<<N_NODES, 320, 0, stream>>>(h2, sq2, sf2, row0, out2);
}

// Round 6
// 1114.716 us; speedup vs baseline: 1.1558x; 1.1558x over previous
//
#include <hip/hip_runtime.h>

namespace {
constexpr int N_NODES = 10000;
constexpr int DEG = 16;
constexpr int D = DEG + 1;            // 17 neighbors incl self-loop
constexpr int F_IN = 512;
constexpr int HID = 16;
constexpr int NC = 32;
constexpr int E0 = N_NODES * DEG;     // 160000
constexpr float SIGB  = 0.10009765625f;    // bf16(0.1)
constexpr float NORMB = 0.058837890625f;   // bf16(bf16(17^-0.5)^2)

// round-to-nearest-even f32 -> bf16 value (kept in f32) — matches ml_dtypes
__device__ __forceinline__ float bfr(float v) {
  unsigned x = __float_as_uint(v);
  x = (x + 0x7fffu + ((x >> 16) & 1u)) & 0xffff0000u;
  return __uint_as_float(x);
}
}  // namespace

// static device scratch (all bf16-valued f32)
__device__ float g_h1[N_NODES * HID];
__device__ float g_r1[N_NODES * HID];
__device__ float g_h2[N_NODES * NC];
__device__ float g_sq1[N_NODES * D];
__device__ float g_sq2[N_NODES * D];
__device__ float g_sf1[N_NODES];
__device__ float g_sf2[N_NODES];

// h1[i][j]: 4 nodes per thread -> 4 independent bf16 chains (ILP), same per-chain order
__global__ void k_lin1(const float* __restrict__ x, const float* __restrict__ W1,
                       const float* __restrict__ b1) {
  int tid = blockIdx.x * blockDim.x + threadIdx.x;
  int j = tid & 15, gi = tid >> 4;
  if (gi >= N_NODES / 4) return;
  int i0 = gi * 4;
  float acc0 = 0.f, acc1 = 0.f, acc2 = 0.f, acc3 = 0.f;
  const float* x0 = x + (size_t)i0 * F_IN;
  for (int k = 0; k < F_IN; ++k) {
    float wk = bfr(W1[k * HID + j]);
    acc0 = bfr(acc0 + bfr(bfr(x0[k]) * wk));
    acc1 = bfr(acc1 + bfr(bfr(x0[k + F_IN]) * wk));
    acc2 = bfr(acc2 + bfr(bfr(x0[k + 2 * F_IN]) * wk));
    acc3 = bfr(acc3 + bfr(bfr(x0[k + 3 * F_IN]) * wk));
  }
  float bb = bfr(b1[j]);
  g_h1[(i0 + 0) * HID + j] = bfr(acc0 + bb);
  g_h1[(i0 + 1) * HID + j] = bfr(acc1 + bb);
  g_h1[(i0 + 2) * HID + j] = bfr(acc2 + bb);
  g_h1[(i0 + 3) * HID + j] = bfr(acc3 + bb);
}

// h2[i][j] = bf16chain( sum_k r1_ik * bf16(W2_kj) ) + bf16(b2_j)
__global__ void k_lin2(const float* __restrict__ W2, const float* __restrict__ b2) {
  int g = blockIdx.x * blockDim.x + threadIdx.x;
  if (g >= N_NODES * NC) return;
  int i = g >> 5, j = g & 31;
  float acc = 0.f;
#pragma unroll
  for (int k = 0; k < HID; ++k) {
    float p = bfr(g_r1[i * HID + k] * bfr(W2[k * NC + j]));
    acc = bfr(acc + p);
  }
  g_h2[g] = bfr(acc + bfr(b2[j]));
}

// Per node i (one wave): tile (padded stride), sq, self-kernel mean (5 interleaved
// p-chains, flat a-major seq-bf16 over 289 in tail), aggregation.
template <int H, bool LOGSM>
__global__ void k_build(const float* __restrict__ hpre, const int* __restrict__ row0,
                        float* __restrict__ selfm, float* __restrict__ sqb,
                        float* __restrict__ relu_out, float* __restrict__ out0) {
  constexpr int HS = H + 1;  // pad: lanes with different rows hit different banks
  __shared__ int nidx[D];
  __shared__ float T[D * HS];
  __shared__ float sq[D];
  __shared__ float sterm[D * D];
  __shared__ float earr[32];
  __shared__ float lsv;
  int i = blockIdx.x, t = threadIdx.x;  // 0..63 (one wave)
  if (t < D) nidx[t] = (t < DEG) ? row0[i * DEG + t] : i;
  __syncthreads();
  for (int e = t; e < D * H; e += 64) {
    int d = e / H, h = e - d * H;
    T[d * HS + h] = hpre[(size_t)nidx[d] * H + h];
  }
  __syncthreads();
  if (t < D) {
    float s = 0.f;  // seq bf16 chain over h ascending
#pragma unroll
    for (int h = 0; h < H; ++h) { float v = T[t * HS + h]; s = bfr(s + bfr(v * v)); }
    sq[t] = s;
    sqb[i * D + t] = s;
  }
  __syncthreads();
  // self-kernel terms: 5 interleaved independent chains per thread (p = t + 64*m)
  {
    constexpr int M = (D * D + 63) / 64;  // 5
    float dots[M];
    int pa[M], pb[M];
#pragma unroll
    for (int m = 0; m < M; ++m) {
      int p = t + 64 * m;
      dots[m] = 0.f;
      pa[m] = (p < D * D) ? (p / D) : 0;
      pb[m] = (p < D * D) ? (p - (p / D) * D) : 0;
    }
#pragma unroll
    for (int q = 0; q < H; ++q) {
#pragma unroll
      for (int m = 0; m < M; ++m)
        dots[m] = bfr(dots[m] + bfr(T[pa[m] * HS + q] * T[pb[m] * HS + q]));
    }
#pragma unroll
    for (int m = 0; m < M; ++m) {
      int p = t + 64 * m;
      if (p < D * D) {
        float d2 = bfr(bfr(sq[pa[m]] + sq[pb[m]]) - bfr(2.f * dots[m]));
        float arg = bfr((-d2) / SIGB);
        sterm[p] = bfr(expf(arg));
      }
    }
  }
  __syncthreads();
  if (t == 0) {  // flat (a-major) seq-bf16 mean over 289
    float s = 0.f;
#pragma unroll 1
    for (int p = 0; p < D * D; ++p) s = bfr(s + sterm[p]);
    selfm[i] = bfr(s / 289.0f);
  }
  // aggregation: seq-bf16 sum, edge order then self-loop
  if constexpr (!LOGSM) {
    if (t < H) {
      float acc = 0.f;
#pragma unroll
      for (int d = 0; d < DEG; ++d) acc = bfr(acc + bfr(NORMB * T[d * HS + t]));
      acc = bfr(acc + bfr(NORMB * T[DEG * HS + t]));
      relu_out[i * H + t] = fmaxf(acc, 0.f);
    }
  } else {
    int j = t & 31;
    float v = 0.f;
#pragma unroll
    for (int d = 0; d < DEG; ++d) v = bfr(v + bfr(NORMB * T[d * HS + j]));
    v = bfr(v + bfr(NORMB * T[DEG * HS + j]));
    float m = v;
#pragma unroll
    for (int off = 32; off; off >>= 1) m = fmaxf(m, __shfl_xor(m, off));
    float sh = bfr(v - m);
    if (t < 32) earr[t] = bfr(expf(sh));
    __syncthreads();
    if (t == 0) {
      float s = 0.f;
#pragma unroll 1
      for (int q = 0; q < 32; ++q) s = bfr(s + earr[q]);
      lsv = bfr(logf(s));
    }
    __syncthreads();
    if (t < 32) out0[i * 32 + t] = bfr(sh - lsv);
  }
}

// Per col-node c: thread (k,a) computes 17 b-dots as INTERLEAVED chains (q outer,
// b inner, dotv[17] accumulators) — identical per-chain bf16 order, 17x ILP.
template <int H>
__global__ void k_cross(const float* __restrict__ hpre, const float* __restrict__ sqb,
                        const float* __restrict__ selfm, const int* __restrict__ row0,
                        float* __restrict__ outm) {
  constexpr int DH = D * H;
  __shared__ float hc[DH];
  __shared__ float sqc[D];
  __shared__ float cterm[DEG * D * D];  // [k][a*17+b]
  int c = blockIdx.x, t = threadIdx.x;  // 0..319
  for (int e = t; e < DH; e += 320) {
    int d = e / H, h = e - d * H;
    int idx = (d < DEG) ? row0[c * DEG + d] : c;
    hc[e] = hpre[(size_t)idx * H + h];
  }
  if (t < D) sqc[t] = sqb[c * D + t];
  __syncthreads();
  if (t < DEG * D) {
    int k = t / D, a = t - k * D;
    int r = row0[c * DEG + k];
    int idx = (a < DEG) ? row0[r * DEG + a] : r;
    const float4* hr4 = reinterpret_cast<const float4*>(hpre + (size_t)idx * H);
    float rv[H];
#pragma unroll
    for (int q4 = 0; q4 < H / 4; ++q4) {
      float4 v = hr4[q4];
      rv[q4 * 4 + 0] = v.x; rv[q4 * 4 + 1] = v.y;
      rv[q4 * 4 + 2] = v.z; rv[q4 * 4 + 3] = v.w;
    }
    float sqra = sqb[r * D + a];
    float dotv[D];
#pragma unroll
    for (int b = 0; b < D; ++b) dotv[b] = 0.f;
#pragma unroll
    for (int q = 0; q < H; ++q) {
      float rq = rv[q];
#pragma unroll
      for (int b = 0; b < D; ++b)  // hc read is wave-uniform -> LDS broadcast
        dotv[b] = bfr(dotv[b] + bfr(rq * hc[b * H + q]));
    }
    float* out_t = cterm + k * (D * D) + a * D;
#pragma unroll
    for (int b = 0; b < D; ++b) {
      float d2 = bfr(bfr(sqra + sqc[b]) - bfr(2.f * dotv[b]));
      float arg = bfr((-d2) / SIGB);
      out_t[b] = bfr(expf(arg));
    }
  }
  __syncthreads();
  if (t < DEG) {
    const float* src = cterm + t * (D * D);
    float s = 0.f;
#pragma unroll 1
    for (int p = 0; p < D * D; ++p) s = bfr(s + src[p]);
    float cross = bfr(s / 289.0f);
    int r = row0[c * DEG + t];
    outm[c * DEG + t] = bfr(bfr(selfm[r] + selfm[c]) - 2.f * cross);
  }
  if (t == DEG) outm[E0 + c] = 0.0f;  // self-loop: chains identical -> exactly 0
}

extern "C" void kernel_launch(void* const* d_in, const int* in_sizes, int n_in,
                              void* d_out, int out_size, void* d_ws, size_t ws_size,
                              hipStream_t stream) {
  const float* x  = (const float*)d_in[0];
  const int* edge_index = (const int*)d_in[1];
  const float* W1 = (const float*)d_in[2];
  const float* b1 = (const float*)d_in[3];
  const float* W2 = (const float*)d_in[4];
  const float* b2 = (const float*)d_in[5];
  const int* row0 = edge_index;
  (void)d_ws; (void)ws_size;

  float *h1, *r1, *h2, *sq1, *sq2, *sf1, *sf2;
  hipGetSymbolAddress((void**)&h1,  HIP_SYMBOL(g_h1));
  hipGetSymbolAddress((void**)&r1,  HIP_SYMBOL(g_r1));
  hipGetSymbolAddress((void**)&h2,  HIP_SYMBOL(g_h2));
  hipGetSymbolAddress((void**)&sq1, HIP_SYMBOL(g_sq1));
  hipGetSymbolAddress((void**)&sq2, HIP_SYMBOL(g_sq2));
  hipGetSymbolAddress((void**)&sf1, HIP_SYMBOL(g_sf1));
  hipGetSymbolAddress((void**)&sf2, HIP_SYMBOL(g_sf2));

  float* out0 = (float*)d_out;             // log_softmax [10000,32]
  float* out1 = out0 + N_NODES * NC;       // mmd1 [170000]
  float* out2 = out1 + (E0 + N_NODES);     // mmd2 [170000]

  k_lin1<<<(N_NODES / 4 * HID + 255) / 256, 256, 0, stream>>>(x, W1, b1);
  k_build<HID, false><<<N_NODES, 64, 0, stream>>>(h1, row0, sf1, sq1, r1, nullptr);
  k_cross<HID><<<N_NODES, 320, 0, stream>>>(h1, sq1, sf1, row0, out1);
  k_lin2<<<(N_NODES * NC + 255) / 256, 256, 0, stream>>>(W2, b2);
  k_build<NC, true><<<N_NODES, 64, 0, stream>>>(h2, row0, sf2, sq2, nullptr, out0);
  k_cross<NC><<<N_NODES, 320, 0, stream>>>(h2, sq2, sf2, row0, out2);
}

// Round 7
// 779.248 us; speedup vs baseline: 1.6534x; 1.4305x over previous
//
#include <hip/hip_runtime.h>

namespace {
constexpr int N_NODES = 10000;
constexpr int DEG = 16;
constexpr int D = DEG + 1;            // 17 neighbors incl self-loop
constexpr int F_IN = 512;
constexpr int HID = 16;
constexpr int NC = 32;
constexpr int E0 = N_NODES * DEG;     // 160000
constexpr float SIGB  = 0.10009765625f;    // bf16(0.1)
constexpr float NORMB = 0.058837890625f;   // bf16(bf16(17^-0.5)^2)

// RNE f32->bf16 via gfx950 HW cvt (2 ops vs 3-op software sequence)
__device__ __forceinline__ float bfr(float v) {
  unsigned r;
  asm("v_cvt_pk_bf16_f32 %0, %1, %2" : "=v"(r) : "v"(v), "v"(v));
  return __uint_as_float(r << 16);
}
// round TWO independent f32 to bf16 in ONE v_cvt_pk_bf16_f32
__device__ __forceinline__ void bfr2(float& a, float& b) {
  unsigned r;
  asm("v_cvt_pk_bf16_f32 %0, %1, %2" : "=v"(r) : "v"(a), "v"(b));
  a = __uint_as_float(r << 16);           // src0 -> low half
  b = __uint_as_float(r & 0xffff0000u);   // src1 -> high half
}
}  // namespace

// static device scratch (all bf16-valued f32)
__device__ float g_h1[N_NODES * HID];
__device__ float g_r1[N_NODES * HID];
__device__ float g_h2[N_NODES * NC];
__device__ float g_sq1[N_NODES * D];
__device__ float g_sq2[N_NODES * D];
__device__ float g_sf1[N_NODES];
__device__ float g_sf2[N_NODES];

// h1: 4 nodes/thread -> 4 chains, rounds paired into cvt_pk
__global__ void k_lin1(const float* __restrict__ x, const float* __restrict__ W1,
                       const float* __restrict__ b1) {
  int tid = blockIdx.x * blockDim.x + threadIdx.x;
  int j = tid & 15, gi = tid >> 4;
  if (gi >= N_NODES / 4) return;
  int i0 = gi * 4;
  float acc0 = 0.f, acc1 = 0.f, acc2 = 0.f, acc3 = 0.f;
  const float* x0 = x + (size_t)i0 * F_IN;
  for (int k = 0; k < F_IN; ++k) {
    float wk = bfr(W1[k * HID + j]);
    float xa = x0[k], xb = x0[k + F_IN], xc = x0[k + 2 * F_IN], xd = x0[k + 3 * F_IN];
    bfr2(xa, xb); bfr2(xc, xd);
    float p0 = xa * wk, p1 = xb * wk, p2 = xc * wk, p3 = xd * wk;
    bfr2(p0, p1); bfr2(p2, p3);
    float s0 = acc0 + p0, s1 = acc1 + p1, s2 = acc2 + p2, s3 = acc3 + p3;
    bfr2(s0, s1); bfr2(s2, s3);
    acc0 = s0; acc1 = s1; acc2 = s2; acc3 = s3;
  }
  float bb = bfr(b1[j]);
  g_h1[(i0 + 0) * HID + j] = bfr(acc0 + bb);
  g_h1[(i0 + 1) * HID + j] = bfr(acc1 + bb);
  g_h1[(i0 + 2) * HID + j] = bfr(acc2 + bb);
  g_h1[(i0 + 3) * HID + j] = bfr(acc3 + bb);
}

__global__ void k_lin2(const float* __restrict__ W2, const float* __restrict__ b2) {
  int g = blockIdx.x * blockDim.x + threadIdx.x;
  if (g >= N_NODES * NC) return;
  int i = g >> 5, j = g & 31;
  float acc = 0.f;
#pragma unroll
  for (int k = 0; k < HID; ++k)
    acc = bfr(acc + bfr(g_r1[i * HID + k] * bfr(W2[k * NC + j])));
  g_h2[g] = bfr(acc + bfr(b2[j]));
}

// Per node i (one wave): tile, sq, self-kernel mean (5 chains, rounds paired),
// aggregation. Chain orders identical to reference.
template <int H, bool LOGSM>
__global__ void k_build(const float* __restrict__ hpre, const int* __restrict__ row0,
                        float* __restrict__ selfm, float* __restrict__ sqb,
                        float* __restrict__ relu_out, float* __restrict__ out0) {
  constexpr int HS = H + 1;
  __shared__ int nidx[D];
  __shared__ __align__(16) float T[D * HS];
  __shared__ float sq[D];
  __shared__ float sterm[D * D];
  __shared__ float earr[32];
  __shared__ float lsv;
  int i = blockIdx.x, t = threadIdx.x;  // 0..63
  if (t < D) nidx[t] = (t < DEG) ? row0[i * DEG + t] : i;
  __syncthreads();
  for (int e = t; e < D * H; e += 64) {
    int d = e / H, h = e - d * H;
    T[d * HS + h] = hpre[(size_t)nidx[d] * H + h];
  }
  __syncthreads();
  if (t < D) {
    float s = 0.f;
#pragma unroll
    for (int h = 0; h < H; ++h) { float v = T[t * HS + h]; s = bfr(s + bfr(v * v)); }
    sq[t] = s;
    sqb[i * D + t] = s;
  }
  __syncthreads();
  {
    constexpr int M = (D * D + 63) / 64;  // 5
    float dots[M];
    int pa[M], pb[M];
#pragma unroll
    for (int m = 0; m < M; ++m) {
      int p = t + 64 * m;
      dots[m] = 0.f;
      pa[m] = (p < D * D) ? (p / D) : 0;
      pb[m] = (p < D * D) ? (p - (p / D) * D) : 0;
    }
#pragma unroll
    for (int q = 0; q < H; ++q) {
      float p0 = T[pa[0] * HS + q] * T[pb[0] * HS + q];
      float p1 = T[pa[1] * HS + q] * T[pb[1] * HS + q];
      float p2 = T[pa[2] * HS + q] * T[pb[2] * HS + q];
      float p3 = T[pa[3] * HS + q] * T[pb[3] * HS + q];
      float p4 = T[pa[4] * HS + q] * T[pb[4] * HS + q];
      bfr2(p0, p1); bfr2(p2, p3); p4 = bfr(p4);
      float s0 = dots[0] + p0, s1 = dots[1] + p1, s2 = dots[2] + p2,
            s3 = dots[3] + p3, s4 = dots[4] + p4;
      bfr2(s0, s1); bfr2(s2, s3); s4 = bfr(s4);
      dots[0] = s0; dots[1] = s1; dots[2] = s2; dots[3] = s3; dots[4] = s4;
    }
#pragma unroll
    for (int m = 0; m < M; ++m) {
      int p = t + 64 * m;
      if (p < D * D) {
        float d2 = bfr(bfr(sq[pa[m]] + sq[pb[m]]) - 2.f * dots[m]);  // 2*bf16 exact
        float arg = bfr((-d2) / SIGB);
        sterm[p] = bfr(expf(arg));
      }
    }
  }
  __syncthreads();
  if (t == 0) {
    float s = 0.f;
#pragma unroll 1
    for (int p = 0; p < D * D; ++p) s = bfr(s + sterm[p]);
    selfm[i] = bfr(s / 289.0f);
  }
  if constexpr (!LOGSM) {
    if (t < H) {
      float acc = 0.f;
#pragma unroll
      for (int d = 0; d < DEG; ++d) acc = bfr(acc + bfr(NORMB * T[d * HS + t]));
      acc = bfr(acc + bfr(NORMB * T[DEG * HS + t]));
      relu_out[i * H + t] = fmaxf(acc, 0.f);
    }
  } else {
    int j = t & 31;
    float v = 0.f;
#pragma unroll
    for (int d = 0; d < DEG; ++d) v = bfr(v + bfr(NORMB * T[d * HS + j]));
    v = bfr(v + bfr(NORMB * T[DEG * HS + j]));
    float m = v;
#pragma unroll
    for (int off = 32; off; off >>= 1) m = fmaxf(m, __shfl_xor(m, off));
    float sh = bfr(v - m);
    if (t < 32) earr[t] = bfr(expf(sh));
    __syncthreads();
    if (t == 0) {
      float s = 0.f;
#pragma unroll 1
      for (int q = 0; q < 32; ++q) s = bfr(s + earr[q]);
      lsv = bfr(logf(s));
    }
    __syncthreads();
    if (t < 32) out0[i * 32 + t] = bfr(sh - lsv);
  }
}

// Per col-node c: 17 b-chains per (k,a) thread; b-pairs share one cvt_pk per round
// and one ds_read_b64 (hc transposed to [q][b], wave-uniform broadcast).
template <int H>
__global__ void k_cross(const float* __restrict__ hpre, const float* __restrict__ sqb,
                        const float* __restrict__ selfm, const int* __restrict__ row0,
                        float* __restrict__ outm) {
  constexpr int STQ = D + 1;  // 18: even stride -> 8B-aligned pairs at even b
  __shared__ __align__(16) float hcT[H * STQ];
  __shared__ float sqc[D];
  __shared__ float cterm[DEG * D * D];
  int c = blockIdx.x, t = threadIdx.x;  // 0..319
  for (int e = t; e < D * H; e += 320) {
    int d = e / H, h = e - d * H;
    int idx = (d < DEG) ? row0[c * DEG + d] : c;
    hcT[h * STQ + d] = hpre[(size_t)idx * H + h];  // transposed: [q][b]
  }
  if (t < D) sqc[t] = sqb[c * D + t];
  __syncthreads();
  if (t < DEG * D) {
    int k = t / D, a = t - k * D;
    int r = row0[c * DEG + k];
    int idx = (a < DEG) ? row0[r * DEG + a] : r;
    const float4* hr4 = reinterpret_cast<const float4*>(hpre + (size_t)idx * H);
    float rv[H];
#pragma unroll
    for (int q4 = 0; q4 < H / 4; ++q4) {
      float4 v = hr4[q4];
      rv[q4 * 4 + 0] = v.x; rv[q4 * 4 + 1] = v.y;
      rv[q4 * 4 + 2] = v.z; rv[q4 * 4 + 3] = v.w;
    }
    float sqra = sqb[r * D + a];
    float dotv[D];
    {  // q = 0: seed chains (bfr(0+p) == p)
      float rq = rv[0];
#pragma unroll
      for (int b = 0; b < DEG; b += 2) {
        float2 h2 = *reinterpret_cast<const float2*>(&hcT[b]);
        float p0 = rq * h2.x, p1 = rq * h2.y;
        bfr2(p0, p1);
        dotv[b] = p0; dotv[b + 1] = p1;
      }
      dotv[16] = bfr(rq * hcT[16]);
    }
#pragma unroll
    for (int q = 1; q < H; ++q) {
      float rq = rv[q];
      const float* rowq = &hcT[q * STQ];
#pragma unroll
      for (int b = 0; b < DEG; b += 2) {
        float2 h2 = *reinterpret_cast<const float2*>(&rowq[b]);
        float p0 = rq * h2.x, p1 = rq * h2.y;
        bfr2(p0, p1);
        float s0 = dotv[b] + p0, s1 = dotv[b + 1] + p1;
        bfr2(s0, s1);
        dotv[b] = s0; dotv[b + 1] = s1;
      }
      dotv[16] = bfr(dotv[16] + bfr(rq * rowq[16]));
    }
    float* out_t = cterm + k * (D * D) + a * D;
#pragma unroll
    for (int b = 0; b < DEG; b += 2) {
      float S0 = sqra + sqc[b], S1 = sqra + sqc[b + 1];
      bfr2(S0, S1);
      float d20 = S0 - 2.f * dotv[b], d21 = S1 - 2.f * dotv[b + 1];  // 2*bf16 exact
      bfr2(d20, d21);
      float a0 = (-d20) / SIGB, a1 = (-d21) / SIGB;
      bfr2(a0, a1);
      float e0 = expf(a0), e1 = expf(a1);
      bfr2(e0, e1);
      out_t[b] = e0; out_t[b + 1] = e1;
    }
    {
      float S = bfr(sqra + sqc[16]);
      float d2 = bfr(S - 2.f * dotv[16]);
      float arg = bfr((-d2) / SIGB);
      out_t[16] = bfr(expf(arg));
    }
  }
  __syncthreads();
  if (t < DEG) {
    const float* src = cterm + t * (D * D);
    float s = 0.f;
#pragma unroll 1
    for (int p = 0; p < D * D; ++p) s = bfr(s + src[p]);
    float cross = bfr(s / 289.0f);
    int r = row0[c * DEG + t];
    outm[c * DEG + t] = bfr(bfr(selfm[r] + selfm[c]) - 2.f * cross);
  }
  if (t == DEG) outm[E0 + c] = 0.0f;  // self-loop: identical chains -> exactly 0
}

extern "C" void kernel_launch(void* const* d_in, const int* in_sizes, int n_in,
                              void* d_out, int out_size, void* d_ws, size_t ws_size,
                              hipStream_t stream) {
  const float* x  = (const float*)d_in[0];
  const int* edge_index = (const int*)d_in[1];
  const float* W1 = (const float*)d_in[2];
  const float* b1 = (const float*)d_in[3];
  const float* W2 = (const float*)d_in[4];
  const float* b2 = (const float*)d_in[5];
  const int* row0 = edge_index;
  (void)d_ws; (void)ws_size;

  float *h1, *r1, *h2, *sq1, *sq2, *sf1, *sf2;
  hipGetSymbolAddress((void**)&h1,  HIP_SYMBOL(g_h1));
  hipGetSymbolAddress((void**)&r1,  HIP_SYMBOL(g_r1));
  hipGetSymbolAddress((void**)&h2,  HIP_SYMBOL(g_h2));
  hipGetSymbolAddress((void**)&sq1, HIP_SYMBOL(g_sq1));
  hipGetSymbolAddress((void**)&sq2, HIP_SYMBOL(g_sq2));
  hipGetSymbolAddress((void**)&sf1, HIP_SYMBOL(g_sf1));
  hipGetSymbolAddress((void**)&sf2, HIP_SYMBOL(g_sf2));

  float* out0 = (float*)d_out;
  float* out1 = out0 + N_NODES * NC;
  float* out2 = out1 + (E0 + N_NODES);

  k_lin1<<<(N_NODES / 4 * HID + 255) / 256, 256, 0, stream>>>(x, W1, b1);
  k_build<HID, false><<<N_NODES, 64, 0, stream>>>(h1, row0, sf1, sq1, r1, nullptr);
  k_cross<HID><<<N_NODES, 320, 0, stream>>>(h1, sq1, sf1, row0, out1);
  k_lin2<<<(N_NODES * NC + 255) / 256, 256, 0, stream>>>(W2, b2);
  k_build<NC, true><<<N_NODES, 64, 0, stream>>>(h2, row0, sf2, sq2, nullptr, out0);
  k_cross<NC><<<N_NODES, 320, 0, stream>>>(h2, sq2, sf2, row0, out2);
}